// Round 10
// baseline (375.484 us; speedup 1.0000x reference)
//
#include <hip/hip_runtime.h>
#include <math.h>

// LGNGuard: 3-layer guarded LightGCN propagation + sigmoid(U @ I^T) scoring.
// Multi-kernel; CSR by src (atomic-free scatter); cos once per undirected edge;
// prune+EMA fused into SpMM; layer-3 SpMM only for selected rows. BF16 table,
// f32 math. Edge loops unrolled x8 (gathers are L2-miss latency/MSHR bound).

#define DD 64
typedef unsigned int u32;

__device__ __forceinline__ float bflo(u32 u) { return __uint_as_float(u << 16); }
__device__ __forceinline__ float bfhi(u32 u) { return __uint_as_float(u & 0xFFFF0000u); }
__device__ __forceinline__ u32 bfpk(float lo, float hi) {   // RNE pack
    u32 a = __float_as_uint(lo), b = __float_as_uint(hi);
    a = (a + 0x7FFFu + ((a >> 16) & 1u)) >> 16;
    b = (b + 0x7FFFu + ((b >> 16) & 1u)) & 0xFFFF0000u;
    return a | b;
}
__device__ __forceinline__ void unp16(uint4 q0, uint4 q1, float* f) {
    f[0]=bflo(q0.x); f[1]=bfhi(q0.x); f[2]=bflo(q0.y); f[3]=bfhi(q0.y);
    f[4]=bflo(q0.z); f[5]=bfhi(q0.z); f[6]=bflo(q0.w); f[7]=bfhi(q0.w);
    f[8]=bflo(q1.x); f[9]=bfhi(q1.x); f[10]=bflo(q1.y); f[11]=bfhi(q1.y);
    f[12]=bflo(q1.z); f[13]=bfhi(q1.z); f[14]=bflo(q1.w); f[15]=bfhi(q1.w);
}

// ================= CSR build =================

__global__ __launch_bounds__(256) void hist_k(const int* __restrict__ src,
                                              int* __restrict__ deg,
                                              int* __restrict__ rank, int E) {
    int e0 = (blockIdx.x * blockDim.x + threadIdx.x) * 2;
    if (e0 + 1 < E) {
        int s0 = src[e0], s1 = src[e0 + 1];
        rank[e0]     = atomicAdd(&deg[s0], 1);
        rank[e0 + 1] = atomicAdd(&deg[s1], 1);
    } else if (e0 < E) {
        rank[e0] = atomicAdd(&deg[src[e0]], 1);
    }
}

__global__ __launch_bounds__(256) void scan1_k(const int* __restrict__ in,
                                               int* __restrict__ out,
                                               int* __restrict__ partial, int M) {
    __shared__ int sh[256];
    int base = blockIdx.x * 1024;
    int t = threadIdx.x;
    int i0 = base + t * 4;
    int v0 = (i0 + 0 < M) ? in[i0 + 0] : 0;
    int v1 = (i0 + 1 < M) ? in[i0 + 1] : 0;
    int v2 = (i0 + 2 < M) ? in[i0 + 2] : 0;
    int v3 = (i0 + 3 < M) ? in[i0 + 3] : 0;
    int tsum = v0 + v1 + v2 + v3;
    sh[t] = tsum;
    __syncthreads();
    for (int off = 1; off < 256; off <<= 1) {
        int x = (t >= off) ? sh[t - off] : 0;
        __syncthreads();
        sh[t] += x;
        __syncthreads();
    }
    int texcl = sh[t] - tsum;
    if (i0 + 0 < M) out[i0 + 0] = texcl;
    if (i0 + 1 < M) out[i0 + 1] = texcl + v0;
    if (i0 + 2 < M) out[i0 + 2] = texcl + v0 + v1;
    if (i0 + 3 < M) out[i0 + 3] = texcl + v0 + v1 + v2;
    if (t == 255) partial[blockIdx.x] = sh[255];
}

__global__ __launch_bounds__(256) void scan2_k(int* __restrict__ partial, int nc) {
    __shared__ int sh[256];
    int t = threadIdx.x;
    int v = (t < nc) ? partial[t] : 0;
    sh[t] = v;
    __syncthreads();
    for (int off = 1; off < 256; off <<= 1) {
        int x = (t >= off) ? sh[t - off] : 0;
        __syncthreads();
        sh[t] += x;
        __syncthreads();
    }
    if (t < nc) partial[t] = sh[t] - v;
}

__global__ __launch_bounds__(256) void scan3_k(int* __restrict__ out,
                                               const int* __restrict__ partial, int M) {
    int i = blockIdx.x * blockDim.x + threadIdx.x;
    if (i < M) out[i] += partial[i >> 10];
}

// two UNDIRECTED edges per thread; no atomics
__global__ __launch_bounds__(256) void scatter_k(const int* __restrict__ src,
                                                 const int* __restrict__ dst,
                                                 const float* __restrict__ adj,
                                                 const int* __restrict__ rp,
                                                 const int* __restrict__ rank,
                                                 int2* __restrict__ ent,
                                                 int* __restrict__ cidx, int EH) {
    int e = (blockIdx.x * blockDim.x + threadIdx.x) * 2;
#pragma unroll
    for (int k = 0; k < 2; ++k, ++e) {
        if (e >= EH) return;
        int u = src[e], i = dst[e];
        int ab = __float_as_int(adj[e]);
        int posU = rp[u] + rank[e];
        int posI = rp[i] + rank[e + EH];
        ent[posU] = make_int2(i, ab);
        ent[posI] = make_int2(u, ab);
        cidx[posI - EH] = posU;
    }
}

// ============ bf16 table + norms + rs-zero + acc-init (fused) ============

__global__ __launch_bounds__(256) void cvt_fused_k(const float* __restrict__ ue,
                                                   const float* __restrict__ ie,
                                                   const int* __restrict__ users,
                                                   const int* __restrict__ items,
                                                   u32* __restrict__ tab,
                                                   float* __restrict__ norms,
                                                   float* __restrict__ rsA,
                                                   float* __restrict__ acc,
                                                   int NU, int Nn, int BU, int BI,
                                                   int cvtBlocks) {
    int b = blockIdx.x;
    if (b < cvtBlocks) {
        int x = b * 256 + threadIdx.x;
        if (x >= Nn * 4) return;
        int node = x >> 2, l4 = x & 3;
        const float4* srow = (node < NU)
            ? (const float4*)(ue + (size_t)node * DD)
            : (const float4*)(ie + (size_t)(node - NU) * DD);
        float f[16];
#pragma unroll
        for (int k = 0; k < 4; ++k) {
            float4 v = srow[l4 * 4 + k];
            f[k*4+0] = v.x; f[k*4+1] = v.y; f[k*4+2] = v.z; f[k*4+3] = v.w;
        }
        uint4 o0, o1;
        o0.x = bfpk(f[0], f[1]);   o0.y = bfpk(f[2], f[3]);
        o0.z = bfpk(f[4], f[5]);   o0.w = bfpk(f[6], f[7]);
        o1.x = bfpk(f[8], f[9]);   o1.y = bfpk(f[10], f[11]);
        o1.z = bfpk(f[12], f[13]); o1.w = bfpk(f[14], f[15]);
        uint4* op = (uint4*)(tab + (size_t)node * 32 + l4 * 8);
        op[0] = o0;
        op[1] = o1;
        float fb[16];
        unp16(o0, o1, fb);
        float s = 0.f;
#pragma unroll
        for (int i = 0; i < 16; ++i) s += fb[i] * fb[i];
        s += __shfl_xor(s, 1, 64);
        s += __shfl_xor(s, 2, 64);
        if (l4 == 0) {
            norms[node] = sqrtf(s);
            if (node >= NU) rsA[node] = 0.f;
        }
    } else {
        int x = (b - cvtBlocks) * 256 + threadIdx.x;
        if (x >= (BU + BI) * 4) return;
        int q_ = x >> 2, l4 = x & 3;
        int node = (q_ < BU) ? users[q_] : (NU + items[q_ - BU]);
        const float4* srow = (node < NU)
            ? (const float4*)(ue + (size_t)node * DD)
            : (const float4*)(ie + (size_t)(node - NU) * DD);
        float4* av = (float4*)acc;
#pragma unroll
        for (int k = 0; k < 4; ++k)
            av[(size_t)q_ * 16 + l4 * 4 + k] = srow[l4 * 4 + k];
    }
}

// ============ cos + rowsums over USER rows (+ acc_upd blocks), unroll x8 ============

__global__ __launch_bounds__(256) void cos_acc_k(const u32* __restrict__ tab,
                                                 const float* __restrict__ norms,
                                                 const int* __restrict__ rp,
                                                 const int2* __restrict__ ent,
                                                 float* __restrict__ cosc,
                                                 float* __restrict__ rowsum,
                                                 const int* __restrict__ users,
                                                 const int* __restrict__ items,
                                                 float* __restrict__ acc,
                                                 int NU, int BU, int BI,
                                                 int cosBlocks) {
    int b = blockIdx.x;
    if (b >= cosBlocks) {   // acc_upd role
        int x = (b - cosBlocks) * 256 + threadIdx.x;
        if (x >= (BU + BI) * 4) return;
        int q_ = x >> 2, l4 = x & 3;
        int node = (q_ < BU) ? users[q_] : (NU + items[q_ - BU]);
        const uint4* p = (const uint4*)(tab + (size_t)node * 32 + l4 * 8);
        float f[16];
        unp16(p[0], p[1], f);
        float4* av = (float4*)acc;
#pragma unroll
        for (int k = 0; k < 4; ++k) {
            float4 o = av[(size_t)q_ * 16 + l4 * 4 + k];
            o.x += f[k * 4 + 0]; o.y += f[k * 4 + 1];
            o.z += f[k * 4 + 2]; o.w += f[k * 4 + 3];
            av[(size_t)q_ * 16 + l4 * 4 + k] = o;
        }
        return;
    }
    int x = b * 256 + threadIdx.x;
    if (x >= NU * 4) return;
    int r = x >> 2, l4 = x & 3;
    int p0 = rp[r], p1 = rp[r + 1];
    const uint4* ap = (const uint4*)(tab + (size_t)r * 32 + l4 * 8);
    float A[16];
    unp16(ap[0], ap[1], A);
    float nr = norms[r];
    float rs = 0.f;
    int p = p0;
    for (; p + 8 <= p1; p += 8) {
        int d[8];
        uint4 ba[8], bbv[8];
#pragma unroll
        for (int k = 0; k < 8; ++k) d[k] = ent[p + k].x;
#pragma unroll
        for (int k = 0; k < 8; ++k) {
            const uint4* q = (const uint4*)(tab + (size_t)d[k] * 32 + l4 * 8);
            ba[k] = q[0]; bbv[k] = q[1];
        }
#pragma unroll
        for (int k = 0; k < 8; ++k) {
            float B[16];
            unp16(ba[k], bbv[k], B);
            float dt = 0.f;
#pragma unroll
            for (int i = 0; i < 16; ++i) dt += A[i] * B[i];
            dt += __shfl_xor(dt, 1, 64);
            dt += __shfl_xor(dt, 2, 64);
            float c = dt / fmaxf(nr * norms[d[k]], 1e-8f);
            if (l4 == 0) {
                cosc[p + k] = c;
                atomicAdd(&rowsum[d[k]], fabsf(c));
            }
            rs += fabsf(c);
        }
    }
    for (; p < p1; ++p) {
        int d = ent[p].x;
        const uint4* q = (const uint4*)(tab + (size_t)d * 32 + l4 * 8);
        uint4 b0 = q[0], b1 = q[1];
        float B[16];
        unp16(b0, b1, B);
        float dot = 0.f;
#pragma unroll
        for (int i = 0; i < 16; ++i) dot += A[i] * B[i];
        dot += __shfl_xor(dot, 1, 64);
        dot += __shfl_xor(dot, 2, 64);
        float c = dot / fmaxf(nr * norms[d], 1e-8f);
        if (l4 == 0) {
            cosc[p] = c;
            atomicAdd(&rowsum[d], fabsf(c));
        }
        rs += fabsf(c);
    }
    if (l4 == 0) rowsum[r] = rs;
}

// ===== fused normalize+prune+EMA+SpMM all rows (+next norms, +rsnext zero), x8 =====

__global__ __launch_bounds__(256) void spmm_fused_k(const u32* __restrict__ tab,
                                                    const int* __restrict__ rp,
                                                    const int2* __restrict__ ent,
                                                    const int* __restrict__ cidx,
                                                    const float* __restrict__ cosc,
                                                    const float* __restrict__ rowsum,
                                                    const float* __restrict__ Wp,
                                                    const float* __restrict__ bp,
                                                    float* __restrict__ memc, int useAdj,
                                                    u32* __restrict__ outtab,
                                                    float* __restrict__ norms,
                                                    float* __restrict__ rsnext,
                                                    int NU, int EH, int N) {
    int x = blockIdx.x * 256 + threadIdx.x;
    if (x >= N * 4) return;
    int r = x >> 2, l4 = x & 3;
    int p0 = rp[r], p1 = rp[r + 1];
    bool isU = (r < NU);
    float w0 = Wp[0], w1 = Wp[1], bb = bp[0];
    float rs  = rowsum[r];
    float rsg = rs > 0.f ? rs : 1.f;
    float a16[16];
#pragma unroll
    for (int i = 0; i < 16; ++i) a16[i] = 0.f;
    int p = p0;
    for (; p + 8 <= p1; p += 8) {
        int2 tt[8];
        uint4 ba[8], bbv[8];
        float cv[8];
#pragma unroll
        for (int k = 0; k < 8; ++k) tt[k] = ent[p + k];
#pragma unroll
        for (int k = 0; k < 8; ++k) {
            const uint4* q = (const uint4*)(tab + (size_t)tt[k].x * 32 + l4 * 8);
            ba[k] = q[0]; bbv[k] = q[1];
        }
#pragma unroll
        for (int k = 0; k < 8; ++k)
            cv[k] = cosc[isU ? (p + k) : cidx[p + k - EH]];
#pragma unroll
        for (int k = 0; k < 8; ++k) {
            float a = __int_as_float(tt[k].y);
            float rd = rowsum[tt[k].x];
            float rdg = rd > 0.f ? rd : 1.f;
            float c  = cv[k] / rsg;
            float cr = cv[k] / rdg;
            float z  = w0 * c + w1 * cr + bb;
            float kept = (z > 0.f) ? c : 0.f;
            float mp = useAdj ? a : memc[p + k];
            float m = 0.5f * mp + 0.5f * kept;
            if (l4 == 0) memc[p + k] = m;
            float g = m * a;
            float B[16];
            unp16(ba[k], bbv[k], B);
#pragma unroll
            for (int i = 0; i < 16; ++i) a16[i] += g * B[i];
        }
    }
    for (; p < p1; ++p) {
        int2 t = ent[p];
        int ci = isU ? p : cidx[p - EH];
        const uint4* q = (const uint4*)(tab + (size_t)t.x * 32 + l4 * 8);
        uint4 b0 = q[0], b1 = q[1];
        float cv = cosc[ci];
        float a = __int_as_float(t.y);
        float rd = rowsum[t.x];
        float rdg = rd > 0.f ? rd : 1.f;
        float c  = cv / rsg;
        float cr = cv / rdg;
        float z  = w0 * c + w1 * cr + bb;
        float kept = (z > 0.f) ? c : 0.f;
        float mp = useAdj ? a : memc[p];
        float m = 0.5f * mp + 0.5f * kept;
        if (l4 == 0) memc[p] = m;
        float g = m * a;
        float B[16];
        unp16(b0, b1, B);
#pragma unroll
        for (int i = 0; i < 16; ++i) a16[i] += g * B[i];
    }
    // fused next-layer norm + rsnext zeroing
    float s = 0.f;
#pragma unroll
    for (int i = 0; i < 16; ++i) s += a16[i] * a16[i];
    s += __shfl_xor(s, 1, 64);
    s += __shfl_xor(s, 2, 64);
    if (l4 == 0) {
        norms[r] = sqrtf(s);
        if (r >= NU) rsnext[r] = 0.f;
    }
    uint4 o0, o1;
    o0.x = bfpk(a16[0], a16[1]);   o0.y = bfpk(a16[2], a16[3]);
    o0.z = bfpk(a16[4], a16[5]);   o0.w = bfpk(a16[6], a16[7]);
    o1.x = bfpk(a16[8], a16[9]);   o1.y = bfpk(a16[10], a16[11]);
    o1.z = bfpk(a16[12], a16[13]); o1.w = bfpk(a16[14], a16[15]);
    uint4* op = (uint4*)(outtab + (size_t)r * 32 + l4 * 8);
    op[0] = o0;
    op[1] = o1;
}

// ===== final layer: SpMM only for selected rows, accumulate into acc =====

__global__ __launch_bounds__(256) void sel_spmm_k(const u32* __restrict__ tab,
                                                  const int* __restrict__ rp,
                                                  const int2* __restrict__ ent,
                                                  const int* __restrict__ cidx,
                                                  const float* __restrict__ cosc,
                                                  const float* __restrict__ rowsum,
                                                  const float* __restrict__ Wp,
                                                  const float* __restrict__ bp,
                                                  const float* __restrict__ memc,
                                                  const int* __restrict__ users,
                                                  const int* __restrict__ items,
                                                  float* __restrict__ acc,
                                                  int BU, int BI, int NU, int EH) {
    int x = blockIdx.x * 256 + threadIdx.x;
    if (x >= (BU + BI) * 4) return;
    int q_ = x >> 2, l4 = x & 3;
    int r = (q_ < BU) ? users[q_] : (NU + items[q_ - BU]);
    int p0 = rp[r], p1 = rp[r + 1];
    bool isU = (r < NU);
    float w0 = Wp[0], w1 = Wp[1], bb = bp[0];
    float rs  = rowsum[r];
    float rsg = rs > 0.f ? rs : 1.f;
    float a16[16];
#pragma unroll
    for (int i = 0; i < 16; ++i) a16[i] = 0.f;
    for (int p = p0; p < p1; ++p) {
        int2 t = ent[p];
        int ci = isU ? p : cidx[p - EH];
        const uint4* q = (const uint4*)(tab + (size_t)t.x * 32 + l4 * 8);
        uint4 b0 = q[0], b1 = q[1];
        float cv = cosc[ci];
        float a = __int_as_float(t.y);
        float rd = rowsum[t.x];
        float rdg = rd > 0.f ? rd : 1.f;
        float c  = cv / rsg;
        float cr = cv / rdg;
        float z  = w0 * c + w1 * cr + bb;
        float kept = (z > 0.f) ? c : 0.f;
        float m = 0.5f * memc[p] + 0.5f * kept;
        float g = m * a;
        float B[16];
        unp16(b0, b1, B);
#pragma unroll
        for (int i = 0; i < 16; ++i) a16[i] += g * B[i];
    }
    float4* av = (float4*)acc;
#pragma unroll
    for (int k = 0; k < 4; ++k) {
        float4 o = av[(size_t)q_ * 16 + l4 * 4 + k];
        o.x += a16[k * 4 + 0]; o.y += a16[k * 4 + 1];
        o.z += a16[k * 4 + 2]; o.w += a16[k * 4 + 3];
        av[(size_t)q_ * 16 + l4 * 4 + k] = o;
    }
}

// ================= final GEMM =================

__global__ __launch_bounds__(256) void final_gemm_k(const float* __restrict__ acc,
                                                    float* __restrict__ out,
                                                    int BU, int BI) {
    __shared__ float Us[64][65];
    __shared__ float Is[64][65];
    int t = threadIdx.x;
    int i0 = blockIdx.y * 64, j0 = blockIdx.x * 64;
#pragma unroll
    for (int i = 0; i < 4; ++i) {
        int f4 = t + i * 256;
        int r = f4 >> 4, c4 = (f4 & 15) * 4;
        float4 u4 = *(const float4*)&acc[(size_t)(i0 + r) * DD + c4];
        float4 v4 = *(const float4*)&acc[(size_t)(BU + j0 + r) * DD + c4];
        Us[r][c4 + 0] = u4.x; Us[r][c4 + 1] = u4.y;
        Us[r][c4 + 2] = u4.z; Us[r][c4 + 3] = u4.w;
        Is[r][c4 + 0] = v4.x; Is[r][c4 + 1] = v4.y;
        Is[r][c4 + 2] = v4.z; Is[r][c4 + 3] = v4.w;
    }
    __syncthreads();
    int tx = t & 15, ty = t >> 4;
    float s[4][4];
#pragma unroll
    for (int i = 0; i < 4; ++i)
#pragma unroll
        for (int j = 0; j < 4; ++j) s[i][j] = 0.f;
    for (int k = 0; k < 64; ++k) {
        float u[4], v[4];
#pragma unroll
        for (int i = 0; i < 4; ++i) u[i] = Us[ty * 4 + i][k];
#pragma unroll
        for (int j = 0; j < 4; ++j) v[j] = Is[tx * 4 + j][k];
#pragma unroll
        for (int i = 0; i < 4; ++i)
#pragma unroll
            for (int j = 0; j < 4; ++j) s[i][j] += u[i] * v[j];
    }
#pragma unroll
    for (int i = 0; i < 4; ++i) {
        float4 o;
        o.x = 1.f / (1.f + expf(-s[i][0] * 0.0625f));
        o.y = 1.f / (1.f + expf(-s[i][1] * 0.0625f));
        o.z = 1.f / (1.f + expf(-s[i][2] * 0.0625f));
        o.w = 1.f / (1.f + expf(-s[i][3] * 0.0625f));
        *(float4*)&out[(size_t)(i0 + ty * 4 + i) * BI + j0 + tx * 4] = o;
    }
}

// ================= launch =================

extern "C" void kernel_launch(void* const* d_in, const int* in_sizes, int n_in,
                              void* d_out, int out_size, void* d_ws, size_t ws_size,
                              hipStream_t stream) {
    const int*   users    = (const int*)d_in[0];
    const int*   items    = (const int*)d_in[1];
    const float* user_emb = (const float*)d_in[2];
    const float* item_emb = (const float*)d_in[3];
    const float* Wp       = (const float*)d_in[4];
    const float* bp       = (const float*)d_in[5];
    const int*   src      = (const int*)d_in[6];
    const int*   dst      = (const int*)d_in[7];
    const float* adj      = (const float*)d_in[9];

    int BU = in_sizes[0];
    int BI = in_sizes[1];
    int NU = in_sizes[2] / DD;
    int NI = in_sizes[3] / DD;
    int Nn = NU + NI;
    int E  = in_sizes[6];
    int EH = E / 2;
    int M  = Nn + 1;
    int Mp = (M + 3) & ~3;

    // ---- workspace (16B-aligned blocks first) ----
    u32*   tabA   = (u32*)d_ws;                              // Nn*32
    u32*   tabB   = tabA + (size_t)Nn * 32;                  // Nn*32
    int2*  ent    = (int2*)(tabB + (size_t)Nn * 32);         // E
    int*   cidx   = (int*)(ent + E);                         // EH
    float* norms  = (float*)(cidx + EH);                     // Nn
    float* rsA    = norms + Nn;                              // Nn
    float* rsB    = rsA + Nn;                                // Nn
    float* cosc   = rsB + Nn;                                // EH
    float* memc   = cosc + EH;                               // E
    float* acc    = memc + E;                                // (BU+BI)*64
    int*   deg    = (int*)(acc + (size_t)(BU + BI) * DD);    // Mp
    int*   rp     = deg + Mp;                                // Mp
    int*   rank   = rp + Mp;                                 // E
    int*   partial= rank + E;                                // 256

    int nc  = (M + 1023) / 1024;

    // ---- CSR build ----
    hipMemsetAsync(deg, 0, sizeof(int) * (size_t)M, stream);
    hist_k<<<(E / 2 + 255) / 256, 256, 0, stream>>>(src, deg, rank, E);
    scan1_k<<<nc, 256, 0, stream>>>(deg, rp, partial, M);
    scan2_k<<<1, 256, 0, stream>>>(partial, nc);
    scan3_k<<<(M + 255) / 256, 256, 0, stream>>>(rp, partial, M);
    scatter_k<<<(EH / 2 + 255) / 256, 256, 0, stream>>>(src, dst, adj, rp, rank,
                                                        ent, cidx, EH);

    // ---- bf16 table + norms + rsA zero + acc init (one launch) ----
    int cvtBlocks = (Nn * 4 + 255) / 256;
    int selBlocks = ((BU + BI) * 4 + 255) / 256;
    cvt_fused_k<<<cvtBlocks + selBlocks, 256, 0, stream>>>(user_emb, item_emb, users,
                                                           items, tabA, norms, rsA, acc,
                                                           NU, Nn, BU, BI, cvtBlocks);

    int cosBlocks = (NU * 4 + 255) / 256;
    int nBlocks   = (Nn * 4 + 255) / 256;

    // layer 0
    cos_acc_k<<<cosBlocks, 256, 0, stream>>>(tabA, norms, rp, ent, cosc, rsA,
                                             users, items, acc, NU, BU, BI, cosBlocks);
    spmm_fused_k<<<nBlocks, 256, 0, stream>>>(tabA, rp, ent, cidx, cosc, rsA, Wp, bp,
                                              memc, 1, tabB, norms, rsB, NU, EH, Nn);
    // layer 1 (cos + piggybacked acc_upd of tabB)
    cos_acc_k<<<cosBlocks + selBlocks, 256, 0, stream>>>(tabB, norms, rp, ent, cosc, rsB,
                                                         users, items, acc, NU, BU, BI,
                                                         cosBlocks);
    spmm_fused_k<<<nBlocks, 256, 0, stream>>>(tabB, rp, ent, cidx, cosc, rsB, Wp, bp,
                                              memc, 0, tabA, norms, rsA, NU, EH, Nn);
    // layer 2 (cos + piggybacked acc_upd of tabA)
    cos_acc_k<<<cosBlocks + selBlocks, 256, 0, stream>>>(tabA, norms, rp, ent, cosc, rsA,
                                                         users, items, acc, NU, BU, BI,
                                                         cosBlocks);
    sel_spmm_k<<<selBlocks, 256, 0, stream>>>(tabA, rp, ent, cidx, cosc, rsA, Wp, bp,
                                              memc, users, items, acc, BU, BI, NU, EH);

    dim3 grid(BI / 64, BU / 64);
    final_gemm_k<<<grid, 256, 0, stream>>>(acc, (float*)d_out, BU, BI);
}